// Round 16
// baseline (23520.082 us; speedup 1.0000x reference)
//
#include <hip/hip_runtime.h>
#include <cmath>

// MessageDecoder: 20-step LSTM greedy decoder, B=32768, H=512, 65 actions.
// Round 16: r15 champion (20.7ms) + AGPR-RMW amortization.
//  - r15 diagnosis: ~100 of 128 accs live in AGPRs; each k4 visit costs a
//    v_accvgpr_read+write pair around 4 FMAs -> density 65%.
//  - fix: unroll k4 x2 with FUSED chains acc=fma4(hb,wb,fma4(ha,wa,acc)):
//    8 FMAs per AGPR round-trip -> junk halves (predicted density ~84%).
//    Bitwise: fused nest == two sequential k4 iterations of r2's chain.
//  - whh64 pair-contiguous pack: 16 float4/thread/k8 at imm offsets 0..240,
//    one pointer bump per k8.
//  - everything else r15 verbatim -> bitwise-r2 output.

#define HH      512
#define G4      2048
#define NACTS   65
#define NAP     80    // Wa padded cols
#define NVOCAB  67
#define MAXLEN  20
#define NB      32768
#define TM      16
#define NTH     256
#define EOS_TOK 0
#define PAD_TOK 65
#define BOS_TOK 66
#define HSTR    516

// gxa4[(a*HH + t)*4 + gate] = emb[a].W_ih[gate*HH+t] + b_ih[c] + b_hh[c]
__global__ void prep_gxa_kernel(const float* __restrict__ emb,
                                const float* __restrict__ W_ih,
                                const float* __restrict__ b_ih,
                                const float* __restrict__ b_hh,
                                float* __restrict__ gxa4) {
  int id = blockIdx.x * blockDim.x + threadIdx.x;
  if (id >= NVOCAB * G4) return;
  int a = id / G4, rem = id - a * G4;
  int t = rem >> 2, gate = rem & 3;
  int c = gate * HH + t;
  const float* e = emb + (size_t)a * HH;
  const float* w = W_ih + (size_t)c * HH;
  float acc = 0.f;
  for (int k = 0; k < HH; ++k) acc = fmaf(e[k], w[k], acc);
  gxa4[id] = acc + b_ih[c] + b_hh[c];
}

// k4-major float4 pack: dst[(k4*cols + c)*4 + j] = src[c*HH + k4*4 + j]
__global__ void prep_w4_kernel(const float* __restrict__ src,
                               float* __restrict__ dst, int cols) {
  int id = blockIdx.x * blockDim.x + threadIdx.x;
  if (id >= cols * HH) return;
  int k4 = id / (cols * 4);
  int rem = id - k4 * cols * 4;
  int c = rem >> 2, j = rem & 3;
  dst[id] = src[(size_t)c * HH + k4 * 4 + j];
}

// pair-contiguous W_hh pack for NTH=256, 2 cols/thread, k8 = pair of k4:
// dst[((k8*256 + t)*64) + (kk*8 + j*4 + g)*4 + e]
//   = W_hh[((g*512 + t + j*256)*512) + (k8*2 + kk)*4 + e]
__global__ void prep_whh64_kernel(const float* __restrict__ W_hh,
                                  float* __restrict__ dst) {
  int id = blockIdx.x * blockDim.x + threadIdx.x;
  if (id >= 64 * 256 * 64) return;        // 1<<20 elements
  int e = id & 3;
  int idx = (id >> 2) & 15;
  int t = (id >> 6) & 255;
  int k8 = id >> 14;
  int kk = idx >> 3, j = (idx >> 2) & 1, g = idx & 3;
  int c = t + j * 256;
  dst[id] = W_hh[((size_t)g * 512 + c) * 512 + (k8 * 2 + kk) * 4 + e];
}

// Wa k4-major pack, zero-padded to NAP cols: dst[(k4*NAP + a)*4 + j]
__global__ void prep_wa4_kernel(const float* __restrict__ Wa,
                                float* __restrict__ dst) {
  int id = blockIdx.x * blockDim.x + threadIdx.x;
  if (id >= (HH / 4) * NAP * 4) return;
  int k4 = id / (NAP * 4);
  int rem = id - k4 * NAP * 4;
  int a = rem >> 2, j = rem & 3;
  dst[id] = (a < NACTS) ? Wa[(size_t)a * HH + k4 * 4 + j] : 0.f;
}

__global__ void ws_sentinel_kernel(float* out) {
  out[threadIdx.x] = 123000.f;
}

// acc = h.w*w.w -> h.z*w.z -> h.y*w.y -> h.x*w.x nested (r2's exact chain)
__device__ __forceinline__ float fma4e(float4 h, float4 w, float acc) {
  return fmaf(h.x, w.x, fmaf(h.y, w.y, fmaf(h.z, w.z, fmaf(h.w, w.w, acc))));
}
#define FMA4(acc, h, wv) acc = fma4e((h), (wv), (acc))

__global__ __launch_bounds__(NTH, 2)
void decode_kernel(const float* __restrict__ encoded,
                   const float* __restrict__ gxa4,
                   const float* __restrict__ whh64, // pair-contiguous pack
                   const float* __restrict__ wc4,   // [(k4*512 + c)*4 + j]
                   const float* __restrict__ wh4,
                   const float* __restrict__ bc,
                   const float* __restrict__ bh,
                   const float* __restrict__ wa4,   // [(k4*80 + a)*4 + j]
                   const float* __restrict__ ba,
                   float* __restrict__ out) {
  __shared__ float sh_h[TM][HSTR];
  __shared__ float sh_logits[TM][NACTS + 3];
  __shared__ int   sh_last[TM];
  __shared__ int   sh_stop[TM];
  __shared__ float sh_ent[TM];
  __shared__ int   sh_len[TM];

  const int t = threadIdx.x;               // owns cols t and t+256
  const int row0 = blockIdx.x * TM;

  // ---- stage encoded[row0:+16][:] into sh_h (coalesced float4) ----
  #pragma unroll
  for (int i = 0; i < (TM * HH / 4) / NTH; ++i) {   // 8 float4s per thread
    int f4 = i * NTH + t;
    int idx = f4 * 4;
    int r = idx >> 9;
    int c = idx & (HH - 1);
    *reinterpret_cast<float4*>(&sh_h[r][c]) =
        *reinterpret_cast<const float4*>(encoded + (size_t)(row0 + r) * HH + c);
  }
  if (t < TM) { sh_last[t] = BOS_TOK; sh_stop[t] = 0; sh_ent[t] = 0.f; sh_len[t] = 0; }
  __syncthreads();

  // ---- h0 = enc@Wc^T + bc ; c0 = enc@Wh^T + bh (reference's intentional swap) ----
  float hacc[2][TM], cacc[2][TM];
  #pragma unroll
  for (int j = 0; j < 2; ++j)
    #pragma unroll
    for (int r = 0; r < TM; ++r) { hacc[j][r] = 0.f; cacc[j][r] = 0.f; }
  #pragma unroll 1
  for (int k4 = 0; k4 < HH / 4; ++k4) {
    const float* wcb = wc4 + ((size_t)k4 * HH + t) * 4;
    const float* whb = wh4 + ((size_t)k4 * HH + t) * 4;
    float4 wc0 = *reinterpret_cast<const float4*>(wcb);
    float4 wc1 = *reinterpret_cast<const float4*>(wcb + 1024);
    float4 wh0 = *reinterpret_cast<const float4*>(whb);
    float4 wh1 = *reinterpret_cast<const float4*>(whb + 1024);
    #pragma unroll
    for (int r = 0; r < TM; ++r) {
      float4 e = *reinterpret_cast<const float4*>(&sh_h[r][k4 * 4]);
      FMA4(hacc[0][r], e, wc0);
      FMA4(hacc[1][r], e, wc1);
      FMA4(cacc[0][r], e, wh0);
      FMA4(cacc[1][r], e, wh1);
    }
  }
  __syncthreads();   // done reading enc from sh_h
  float cst[2][TM];
  {
    float bc0 = bc[t], bc1 = bc[t + 256];
    float bh0 = bh[t], bh1 = bh[t + 256];
    #pragma unroll
    for (int r = 0; r < TM; ++r) {
      sh_h[r][t] = hacc[0][r] + bc0;
      sh_h[r][t + 256] = hacc[1][r] + bc1;
      cst[0][r] = cacc[0][r] + bh0;
      cst[1][r] = cacc[1][r] + bh1;
    }
  }
  __syncthreads();

  // ---- 20 decode steps ----
  for (int step = 0; step < MAXLEN; ++step) {
    // x-side gates: two float4 gathers per row (i,f,g,o interleaved)
    float ai[2][TM], af[2][TM], ag[2][TM], ao[2][TM];
    #pragma unroll
    for (int r = 0; r < TM; ++r) {
      const float* g0 = gxa4 + ((size_t)sh_last[r] * HH + t) * 4;
      float4 ga = *reinterpret_cast<const float4*>(g0);
      float4 gb = *reinterpret_cast<const float4*>(g0 + 1024);
      ai[0][r] = ga.x; af[0][r] = ga.y; ag[0][r] = ga.z; ao[0][r] = ga.w;
      ai[1][r] = gb.x; af[1][r] = gb.y; ag[1][r] = gb.z; ao[1][r] = gb.w;
    }
    // gates += h @ W_hh^T ; k4 unrolled x2, fused chains: 8 FMAs per
    // accumulator visit -> halved v_accvgpr RMW traffic. Bitwise == r2.
    {
      const float4* wp = reinterpret_cast<const float4*>(whh64) + (size_t)t * 16;
      #pragma unroll 1
      for (int k8 = 0; k8 < HH / 8; ++k8, wp += 4096) {
        float4 wi0a = wp[0],  wf0a = wp[1],  wg0a = wp[2],  wo0a = wp[3];
        float4 wi1a = wp[4],  wf1a = wp[5],  wg1a = wp[6],  wo1a = wp[7];
        float4 wi0b = wp[8],  wf0b = wp[9],  wg0b = wp[10], wo0b = wp[11];
        float4 wi1b = wp[12], wf1b = wp[13], wg1b = wp[14], wo1b = wp[15];
        const int ka = k8 * 8;
        #pragma unroll
        for (int r = 0; r < TM; ++r) {
          float4 ha = *reinterpret_cast<const float4*>(&sh_h[r][ka]);
          float4 hb = *reinterpret_cast<const float4*>(&sh_h[r][ka + 4]);
          ai[0][r] = fma4e(hb, wi0b, fma4e(ha, wi0a, ai[0][r]));
          af[0][r] = fma4e(hb, wf0b, fma4e(ha, wf0a, af[0][r]));
          ag[0][r] = fma4e(hb, wg0b, fma4e(ha, wg0a, ag[0][r]));
          ao[0][r] = fma4e(hb, wo0b, fma4e(ha, wo0a, ao[0][r]));
          ai[1][r] = fma4e(hb, wi1b, fma4e(ha, wi1a, ai[1][r]));
          af[1][r] = fma4e(hb, wf1b, fma4e(ha, wf1a, af[1][r]));
          ag[1][r] = fma4e(hb, wg1b, fma4e(ha, wg1a, ag[1][r]));
          ao[1][r] = fma4e(hb, wo1b, fma4e(ha, wo1a, ao[1][r]));
        }
      }
    }
    __syncthreads();   // all lanes done reading old sh_h

    // pointwise LSTM cell; write new h  (identical arithmetic to r2)
    #pragma unroll
    for (int j = 0; j < 2; ++j) {
      int col = t + j * 256;
      #pragma unroll
      for (int r = 0; r < TM; ++r) {
        float iv = 1.f / (1.f + expf(-ai[j][r]));
        float fv = 1.f / (1.f + expf(-af[j][r]));
        float gv = tanhf(ag[j][r]);
        float ov = 1.f / (1.f + expf(-ao[j][r]));
        float cn = fmaf(fv, cst[j][r], iv * gv);
        cst[j][r] = cn;
        sh_h[r][col] = ov * tanhf(cn);
      }
    }
    __syncthreads();   // new h visible

    // logits = h @ Wa^T + ba ; direct coalesced reads of k4-major wa4
    // thread (r_lg, a_lg) computes actions a_lg, a_lg+16, ..., a_lg+64
    {
      const int r_lg = t >> 4;     // 0..15
      const int a_lg = t & 15;     // 0..15
      #pragma unroll 1
      for (int ab = 0; ab < 5; ++ab) {
        int a = ab * 16 + a_lg;    // 0..79 (>=65 are zero-padded cols)
        float acc = 0.f;
        #pragma unroll 4
        for (int k4 = 0; k4 < HH / 4; ++k4) {
          float4 h4 = *reinterpret_cast<const float4*>(&sh_h[r_lg][k4 * 4]);
          float4 w4 = *reinterpret_cast<const float4*>(wa4 + ((size_t)k4 * NAP + a) * 4);
          FMA4(acc, h4, w4);
        }
        if (a < NACTS) sh_logits[r_lg][a] = acc + ba[a];
      }
    }
    __syncthreads();

    // per-row softmax / argmax / entropy / state update (r2 verbatim)
    if (t < TM) {
      const int r = t;
      float m = sh_logits[r][0];
      int am = 0;
      #pragma unroll 1
      for (int a = 1; a < NACTS; ++a) {
        float v = sh_logits[r][a];
        if (v > m) { m = v; am = a; }
      }
      float s = 0.f;
      #pragma unroll 1
      for (int a = 0; a < NACTS; ++a) s += expf(sh_logits[r][a] - m);
      float logZ = m + logf(s);
      float pl = 0.f;
      #pragma unroll 1
      for (int a = 0; a < NACTS; ++a) {
        float l = sh_logits[r][a];
        pl = fmaf(expf(l - logZ), l, pl);
      }
      float ent = logZ - pl;
      int stopped = sh_stop[r];
      float lp   = stopped ? 0.f : (sh_logits[r][am] - logZ);
      float entc = stopped ? 0.f : ent;
      int act = stopped ? PAD_TOK : am;
      int grow = row0 + r;
      out[NB + (size_t)grow * MAXLEN + step] = lp;                        // log_probs
      out[NB + (size_t)NB * MAXLEN + (size_t)grow * MAXLEN + step] = (float)act;  // message
      sh_ent[r] += entc;
      if (act != PAD_TOK) sh_len[r] += 1;
      if (act == EOS_TOK) sh_stop[r] = 1;
      sh_last[r] = act;
    }
    __syncthreads();
  }

  if (t < TM) {
    int r = t, grow = row0 + r;
    float lenf = (float)sh_len[r];
    out[grow] = sh_ent[r] / lenf;                           // entropy
    out[NB + 2 * (size_t)NB * MAXLEN + grow] = lenf;        // message_len
  }
}

extern "C" void kernel_launch(void* const* d_in, const int* in_sizes, int n_in,
                              void* d_out, int out_size, void* d_ws, size_t ws_size,
                              hipStream_t stream) {
  const float* encoded = (const float*)d_in[0];
  const float* emb     = (const float*)d_in[1];
  const float* W_ih    = (const float*)d_in[2];
  const float* W_hh    = (const float*)d_in[3];
  const float* b_ih    = (const float*)d_in[4];
  const float* b_hh    = (const float*)d_in[5];
  const float* Wc      = (const float*)d_in[6];
  const float* bc      = (const float*)d_in[7];
  const float* Wh      = (const float*)d_in[8];
  const float* bh      = (const float*)d_in[9];
  const float* Wa      = (const float*)d_in[10];
  const float* ba      = (const float*)d_in[11];
  float* out = (float*)d_out;

  size_t need = ((size_t)NVOCAB * G4 + (size_t)G4 * HH + 2 * (size_t)HH * HH
                 + (size_t)(HH / 4) * NAP * 4) * 4;
  if (ws_size < need) {
    ws_sentinel_kernel<<<1, 64, 0, stream>>>(out);
    return;
  }

  float* ws    = (float*)d_ws;
  float* gxa4  = ws;                          // 67*2048
  float* whh64 = gxa4 + NVOCAB * G4;          // 2048*512 (pair-contiguous pack)
  float* wc4   = whh64 + (size_t)HH * G4;     // 512*512
  float* wh4   = wc4 + (size_t)HH * HH;       // 512*512
  float* wa4   = wh4 + (size_t)HH * HH;       // 128*80*4

  prep_gxa_kernel<<<(NVOCAB * G4 + 255) / 256, 256, 0, stream>>>(emb, W_ih, b_ih, b_hh, gxa4);
  prep_whh64_kernel<<<(64 * 256 * 64 + 255) / 256, 256, 0, stream>>>(W_hh, whh64);
  prep_w4_kernel<<<(HH * HH + 255) / 256, 256, 0, stream>>>(Wc, wc4, HH);
  prep_w4_kernel<<<(HH * HH + 255) / 256, 256, 0, stream>>>(Wh, wh4, HH);
  prep_wa4_kernel<<<((HH / 4) * NAP * 4 + 255) / 256, 256, 0, stream>>>(Wa, wa4);

  decode_kernel<<<NB / TM, NTH, 0, stream>>>(encoded, gxa4, whh64, wc4, wh4,
                                             bc, bh, wa4, ba, out);
}